// Round 3
// baseline (428.224 us; speedup 1.0000x reference)
//
#include <hip/hip_runtime.h>
#include <hip/hip_bf16.h>
#include <hip/hip_cooperative_groups.h>

constexpr int kNN  = 10000;   // nodes
constexpr int kTT  = 12;      // timesteps
constexpr int kFIN = 32;      // input features
constexpr int kHH  = 64;      // hidden
constexpr int kH4  = 256;     // 4*hidden (gates)
constexpr int kOUT = 16;      // output features
constexpr int kNE  = 160000;  // edges
constexpr int kPB  = 512;     // k_prep grid (cooperative: 2 blocks/CU, trivially resident)

typedef _Float16 half8 __attribute__((ext_vector_type(8)));
typedef _Float16 half4 __attribute__((ext_vector_type(4)));
typedef _Float16 half2t __attribute__((ext_vector_type(2)));
typedef float floatx4 __attribute__((ext_vector_type(4)));

// v_rcp_f32-based activations: without -ffast-math a plain fdiv expands to the
// ~10-instr IEEE div sequence; rcp is 1 instr with ~1e-7 rel err.
__device__ __forceinline__ float rcp_fast(float x){ return __builtin_amdgcn_rcpf(x); }
__device__ __forceinline__ float sigf(float x){ return rcp_fast(1.f+__expf(-x)); }
__device__ __forceinline__ float tanh_fast(float x){
  float xc = fminf(fmaxf(x,-30.f),30.f);
  float e = __expf(-2.f*xc);
  return (1.f-e)*rcp_fast(1.f+e);
}

// ONE cooperative kernel for the whole CSR prologue (was: memset + detect_cast
// + deg + scan + scatter = 5 dispatches with drain gaps between each).
// Phase A: zero cnt/cur + int64-detect partials (pb[], no init needed).
// Phase B: reduce pb -> is64 (per-block, in-register), degree atomics.
// Phase C: block 0 runs the serial scan + dis while blocks 1..N-1 do the
//          25MB x->fp16 cast (overlaps the previously idle-machine scan).
// Phase D: CSR scatter (cur zeroed in A, offs/dis from C).
__global__ __launch_bounds__(256) void k_prep(const int* __restrict__ ei,
        const float* __restrict__ x, _Float16* __restrict__ xh,
        int* __restrict__ cnt, int* __restrict__ cur,
        int* __restrict__ offs, float* __restrict__ dis,
        int2* __restrict__ edat, int* __restrict__ pb){
  cooperative_groups::grid_group grid = cooperative_groups::this_grid();
  __shared__ int bf;
  __shared__ int wsum[4];
  int tid = threadIdx.x;
  int nb = gridDim.x;
  int gidx = blockIdx.x*256 + tid;
  int gstride = nb*256;

  // ---- phase A ----
  for (int i = gidx; i < kNN; i += gstride) cnt[i] = 0;
  for (int i = gidx; i < kNN; i += gstride) cur[i] = 0;
  int a = 0;
  for (int i = gidx; i < kNE; i += gstride) a |= ei[2*i+1];
  if (tid == 0) bf = 0;
  __syncthreads();
  if (a) atomicOr(&bf, 1);
  __syncthreads();
  if (tid == 0) pb[blockIdx.x] = bf;
  grid.sync();

  // ---- phase B ----
  int v = 0;
  for (int i = tid; i < nb; i += 256) v |= pb[i];
  if (tid == 0) bf = 0;
  __syncthreads();
  if (v) atomicOr(&bf, 1);
  __syncthreads();
  const bool is64 = (bf == 0);   // odd words all zero <=> int64 input
  for (int e = gidx; e < kNE; e += gstride){
    int c = is64 ? ei[2*(kNE+e)] : ei[kNE+e];
    atomicAdd(&cnt[c], 1);
  }
  grid.sync();

  // ---- phase C ----
  if (blockIdx.x == 0){
    // exclusive scan of in-degree + dis = rsqrt(deg+selfloop)
    const int CH = (kNN + 255)/256;
    int lo = tid*CH, hi = min(lo+CH, kNN);
    int s = 0;
    for (int i = lo; i < hi; ++i) s += cnt[i];
    int orig = s;
    int lane = tid & 63, wv = tid >> 6;
    #pragma unroll
    for (int d = 1; d < 64; d <<= 1){
      int u = __shfl_up(s, d, 64);
      if (lane >= d) s += u;
    }
    if (lane == 63) wsum[wv] = s;
    __syncthreads();
    int add = 0;
    for (int k2 = 0; k2 < wv; ++k2) add += wsum[k2];
    int run = s - orig + add;
    for (int i = lo; i < hi; ++i){ offs[i] = run; run += cnt[i]; }
    if (hi == kNN) offs[kNN] = run;
    for (int i = tid; i < kNN; i += 256) dis[i] = rsqrtf((float)(cnt[i]+1));
  } else {
    // x fp32 -> fp16 cast on the other blocks (overlaps the scan)
    const int NV = kNN*kTT*kFIN/4;
    for (int i = (blockIdx.x-1)*256 + tid; i < NV; i += (nb-1)*256){
      float4 vv = *(const float4*)&x[4*i];
      half4 h;
      h[0]=(_Float16)vv.x; h[1]=(_Float16)vv.y; h[2]=(_Float16)vv.z; h[3]=(_Float16)vv.w;
      *(half4*)&xh[4*i] = h;
    }
  }
  grid.sync();

  // ---- phase D ----
  for (int e = gidx; e < kNE; e += gstride){
    int r = is64 ? ei[2*e]       : ei[e];
    int c = is64 ? ei[2*(kNE+e)] : ei[kNE+e];
    int p2 = offs[c] + atomicAdd(&cur[c], 1);
    edat[p2] = make_int2(r, __float_as_int(dis[r]*dis[c]));
  }
}

// Pure GCN aggregation (no bias/relu — GEMM epilogue handles those since
// A_hat(xW) = (A_hat x)W). t-major in/out so each t-slab is L2-resident.
// Each wave now walks TWO consecutive nodes with interleaved unroll-4 load
// batches: two independent latency chains per wave (the walk is
// latency-bound, ~17 L2-dependent edges/node), and half the wave count.
template<int F>
__global__ __launch_bounds__(256) void k_agg(const _Float16* __restrict__ hin,
                     _Float16* __restrict__ hout,
                     const float* __restrict__ dis,
                     const int* __restrict__ offs, const int2* __restrict__ edat){
  constexpr int LPF = F/2;            // lanes per timestep
  constexpr int TPW = 64/LPF;         // timesteps per wave
  constexpr int NP  = kNN/2;          // node pairs
  int wid = threadIdx.x >> 6, lane = threadIdx.x & 63;
  int gw = blockIdx.x*4 + wid;        // gw = tq*NP + np
  int tq = gw / NP, np = gw - tq*NP;
  int n0 = 2*np, n1 = n0 + 1;
  int fp = lane & (LPF-1), tsub = lane / LPF;
  int t = TPW*tq + tsub;
  const _Float16* hb = hin + (size_t)t*kNN*F;
  float dA = dis[n0], dB = dis[n1];
  half2t svA = *(const half2t*)&hb[(size_t)n0*F + 2*fp];
  half2t svB = *(const half2t*)&hb[(size_t)n1*F + 2*fp];
  float a0 = dA*dA*(float)svA[0], a1 = dA*dA*(float)svA[1];
  float b0 = dB*dB*(float)svB[0], b1 = dB*dB*(float)svB[1];
  int eA  = __builtin_amdgcn_readfirstlane(offs[n0]);
  int eM  = __builtin_amdgcn_readfirstlane(offs[n1]);
  int e1B = __builtin_amdgcn_readfirstlane(offs[n1+1]);
  int e1A = eM, eB = eM;
  // interleaved dual-chain unroll-4 (8 loads in flight per stage)
  while (eA + 4 <= e1A && eB + 4 <= e1B){
    int2 dA4[4], dB4[4];
    #pragma unroll
    for (int u = 0; u < 4; ++u) dA4[u] = edat[eA+u];
    #pragma unroll
    for (int u = 0; u < 4; ++u) dB4[u] = edat[eB+u];
    half2t vA[4], vB[4];
    #pragma unroll
    for (int u = 0; u < 4; ++u) vA[u] = *(const half2t*)&hb[(size_t)dA4[u].x*F + 2*fp];
    #pragma unroll
    for (int u = 0; u < 4; ++u) vB[u] = *(const half2t*)&hb[(size_t)dB4[u].x*F + 2*fp];
    #pragma unroll
    for (int u = 0; u < 4; ++u){
      float wA = __int_as_float(dA4[u].y), wB = __int_as_float(dB4[u].y);
      a0 = fmaf(wA, (float)vA[u][0], a0);
      a1 = fmaf(wA, (float)vA[u][1], a1);
      b0 = fmaf(wB, (float)vB[u][0], b0);
      b1 = fmaf(wB, (float)vB[u][1], b1);
    }
    eA += 4; eB += 4;
  }
  // drain A
  for (; eA + 4 <= e1A; eA += 4){
    int2 d4[4];
    #pragma unroll
    for (int u = 0; u < 4; ++u) d4[u] = edat[eA+u];
    half2t vv[4];
    #pragma unroll
    for (int u = 0; u < 4; ++u) vv[u] = *(const half2t*)&hb[(size_t)d4[u].x*F + 2*fp];
    #pragma unroll
    for (int u = 0; u < 4; ++u){
      float wu = __int_as_float(d4[u].y);
      a0 = fmaf(wu, (float)vv[u][0], a0);
      a1 = fmaf(wu, (float)vv[u][1], a1);
    }
  }
  for (; eA < e1A; ++eA){
    int2 du = edat[eA];
    float wu = __int_as_float(du.y);
    half2t vu = *(const half2t*)&hb[(size_t)du.x*F + 2*fp];
    a0 = fmaf(wu, (float)vu[0], a0);
    a1 = fmaf(wu, (float)vu[1], a1);
  }
  // drain B
  for (; eB + 4 <= e1B; eB += 4){
    int2 d4[4];
    #pragma unroll
    for (int u = 0; u < 4; ++u) d4[u] = edat[eB+u];
    half2t vv[4];
    #pragma unroll
    for (int u = 0; u < 4; ++u) vv[u] = *(const half2t*)&hb[(size_t)d4[u].x*F + 2*fp];
    #pragma unroll
    for (int u = 0; u < 4; ++u){
      float wu = __int_as_float(d4[u].y);
      b0 = fmaf(wu, (float)vv[u][0], b0);
      b1 = fmaf(wu, (float)vv[u][1], b1);
    }
  }
  for (; eB < e1B; ++eB){
    int2 du = edat[eB];
    float wu = __int_as_float(du.y);
    half2t vu = *(const half2t*)&hb[(size_t)du.x*F + 2*fp];
    b0 = fmaf(wu, (float)vu[0], b0);
    b1 = fmaf(wu, (float)vu[1], b1);
  }
  half2t oA; oA[0] = (_Float16)a0; oA[1] = (_Float16)a1;
  *(half2t*)&hout[((size_t)t*kNN + n0)*F + 2*fp] = oA;
  half2t oB; oB[0] = (_Float16)b0; oB[1] = (_Float16)b1;
  *(half2t*)&hout[((size_t)t*kNN + n1)*F + 2*fp] = oB;
}

// Tiled GEMM: out[M,N] = relu(in[M,K] @ W[K,N] + bias), fp16 in/out, fp32 acc.
// Rows m are t-major (m = t*kNN + n). NM: store node-major ((n*T+t)*N).
template<int K, int N, bool NM>
__global__ __launch_bounds__(256) void k_gemm(const _Float16* __restrict__ in,
                      const float* __restrict__ Wg, const float* __restrict__ bias,
                      _Float16* __restrict__ out){
  constexpr int COLG = N/4;
  constexpr int ROWG = 256/COLG;
  constexpr int MR   = 4;
  constexpr int MTILE= ROWG*MR;       // 64
  constexpr int AP   = K + 4;
  __shared__ float Wl[K*N];
  __shared__ float Al[MTILE*AP];
  int tid = threadIdx.x;
  int m0 = blockIdx.x*MTILE;
  for (int idx = tid; idx < MTILE*K/8; idx += 256){
    int r = idx/(K/8), k8 = idx - r*(K/8);
    half8 v = *(const half8*)&in[(size_t)(m0 + r)*K + k8*8];
    float* dst = &Al[r*AP + k8*8];
    #pragma unroll
    for (int j = 0; j < 8; ++j) dst[j] = (float)v[j];
  }
  for (int idx = tid; idx < K*N; idx += 256) Wl[idx] = Wg[idx];
  __syncthreads();
  int cg = tid % COLG, rg = tid / COLG;
  int c0 = cg*4, r0 = rg*MR;
  float acc[MR][4];
  #pragma unroll
  for (int r=0;r<MR;++r){acc[r][0]=0.f;acc[r][1]=0.f;acc[r][2]=0.f;acc[r][3]=0.f;}
  #pragma unroll 2
  for (int k = 0; k < K; k += 4){
    float4 wv[4];
    #pragma unroll
    for (int kk = 0; kk < 4; ++kk) wv[kk] = *(const float4*)&Wl[(k+kk)*N + c0];
    #pragma unroll
    for (int r = 0; r < MR; ++r){
      float4 a4 = *(const float4*)&Al[(r0+r)*AP + k];
      acc[r][0] = fmaf(a4.x, wv[0].x, acc[r][0]);
      acc[r][1] = fmaf(a4.x, wv[0].y, acc[r][1]);
      acc[r][2] = fmaf(a4.x, wv[0].z, acc[r][2]);
      acc[r][3] = fmaf(a4.x, wv[0].w, acc[r][3]);
      acc[r][0] = fmaf(a4.y, wv[1].x, acc[r][0]);
      acc[r][1] = fmaf(a4.y, wv[1].y, acc[r][1]);
      acc[r][2] = fmaf(a4.y, wv[1].z, acc[r][2]);
      acc[r][3] = fmaf(a4.y, wv[1].w, acc[r][3]);
      acc[r][0] = fmaf(a4.z, wv[2].x, acc[r][0]);
      acc[r][1] = fmaf(a4.z, wv[2].y, acc[r][1]);
      acc[r][2] = fmaf(a4.z, wv[2].z, acc[r][2]);
      acc[r][3] = fmaf(a4.z, wv[2].w, acc[r][3]);
      acc[r][0] = fmaf(a4.w, wv[3].x, acc[r][0]);
      acc[r][1] = fmaf(a4.w, wv[3].y, acc[r][1]);
      acc[r][2] = fmaf(a4.w, wv[3].z, acc[r][2]);
      acc[r][3] = fmaf(a4.w, wv[3].w, acc[r][3]);
    }
  }
  float4 bb = *(const float4*)&bias[c0];
  #pragma unroll
  for (int r = 0; r < MR; ++r){
    half4 hv;
    hv[0]=(_Float16)fmaxf(acc[r][0]+bb.x, 0.f);
    hv[1]=(_Float16)fmaxf(acc[r][1]+bb.y, 0.f);
    hv[2]=(_Float16)fmaxf(acc[r][2]+bb.z, 0.f);
    hv[3]=(_Float16)fmaxf(acc[r][3]+bb.w, 0.f);
    int m = m0 + r0 + r;
    size_t oi;
    if (NM){ int t = m/kNN, n = m - t*kNN; oi = ((size_t)n*kTT + t)*N + c0; }
    else    oi = (size_t)m*N + c0;
    *(half4*)&out[oi] = hv;
  }
}

// Fused 2-layer LSTM + FC, THREE 16-node tiles per block (48 nodes).
// Block = 512 thr = 8 waves; waves 0-3 layer0, 4-7 layer1 one t behind,
// h exchanged through per-tile double-buffered LDS.
// launch_bounds(512,2): full 256-reg budget, NO spill; grid 209 <= 256 CUs
// runs in one dispatch round (round-2 verified: 44.5us, VGPR=92).
constexpr int kNU = 3;                         // tiles per block
__global__ __launch_bounds__(512, 2) void k_rec2(const _Float16* __restrict__ xin,
                     const float* __restrict__ wih0, const float* __restrict__ whh0,
                     const float* __restrict__ bih0, const float* __restrict__ bhh0,
                     const float* __restrict__ wih1, const float* __restrict__ whh1,
                     const float* __restrict__ bih1, const float* __restrict__ bhh1,
                     const float* __restrict__ fcw, const float* __restrict__ fcb,
                     float* __restrict__ out){
  constexpr int LP = 72;                       // LDS row pitch (halves)
  __shared__ _Float16 h0b[kNU][2][16*LP];      // [tile][dbuf]
  __shared__ _Float16 h1b[kNU][2][16*LP];
  int tid = threadIdx.x, w = tid >> 6, lane = tid & 63;
  int lo = lane & 15, hi4 = lane >> 4;
  int layer = w >> 2, wl = w & 3;
  int nb0 = blockIdx.x*(16*kNU);

  const float* wih = layer ? wih1 : wih0;
  const float* whh = layer ? whh1 : whh0;
  const float* bi_ = layer ? bih1 : bih0;
  const float* bh_ = layer ? bhh1 : bhh0;

  half8 BI[4][2], BH[4][2];
  #pragma unroll
  for (int q = 0; q < 4; ++q){
    int row = q*kHH + wl*16 + lo;
    #pragma unroll
    for (int kt = 0; kt < 2; ++kt){
      const float* pi = wih + (size_t)row*kHH + kt*32 + hi4*8;
      const float* ph = whh + (size_t)row*kHH + kt*32 + hi4*8;
      half8 fi, fh;
      #pragma unroll
      for (int j = 0; j < 8; ++j){ fi[j] = (_Float16)pi[j]; fh[j] = (_Float16)ph[j]; }
      BI[q][kt] = fi; BH[q][kt] = fh;
    }
  }
  float bias[4];
  #pragma unroll
  for (int q = 0; q < 4; ++q){
    int col = q*kHH + wl*16 + lo;
    bias[q] = bi_[col] + bh_[col];
  }

  float c[kNU][4];
  #pragma unroll
  for (int u = 0; u < kNU; ++u){c[u][0]=0.f;c[u][1]=0.f;c[u][2]=0.f;c[u][3]=0.f;}
  half8 ax[kNU][2];

  const _Float16* xrow[kNU];
  #pragma unroll
  for (int u = 0; u < kNU; ++u)
    xrow[u] = xin + (size_t)min(nb0 + u*16 + lo, kNN-1)*kTT*kHH;
  if (layer == 0){
    #pragma unroll
    for (int u = 0; u < kNU; ++u)
      #pragma unroll
      for (int kt = 0; kt < 2; ++kt)
        ax[u][kt] = *(const half8*)&xrow[u][kt*32 + hi4*8];
  }

  for (int i = 0; i < 13; ++i){
    int t = layer ? i-1 : i;
    bool act = layer ? (i >= 1) : (i < 12);
    if (act){
      #pragma unroll
      for (int u = 0; u < kNU; ++u){
        // layer1 input = h0(t), written by layer0 in iter i-1 (buf t&1);
        // layer0 this iter writes buf (t+1)&1 -> no race.
        if (layer){
          const _Float16* rb = &h0b[u][t & 1][0];
          #pragma unroll
          for (int kt = 0; kt < 2; ++kt)
            ax[u][kt] = *(const half8*)&rb[lo*LP + kt*32 + hi4*8];
        }
        half8 ah[2];
        if (t > 0){
          // recurrent h(t-1): buf (t-1)&1, written iter i-1; this iter writes
          // buf t&1 -> no race.
          const _Float16* rb = layer ? &h1b[u][(t-1) & 1][0] : &h0b[u][(t-1) & 1][0];
          #pragma unroll
          for (int kt = 0; kt < 2; ++kt)
            ah[kt] = *(const half8*)&rb[lo*LP + kt*32 + hi4*8];
        }
        floatx4 acc[4];
        #pragma unroll
        for (int q = 0; q < 4; ++q){
          floatx4 a = {bias[q], bias[q], bias[q], bias[q]};
          a = __builtin_amdgcn_mfma_f32_16x16x32_f16(ax[u][0], BI[q][0], a, 0,0,0);
          a = __builtin_amdgcn_mfma_f32_16x16x32_f16(ax[u][1], BI[q][1], a, 0,0,0);
          acc[q] = a;
        }
        // prefetch next-t x into the just-consumed ax regs (overlaps h-MFMA +
        // epilogue + barrier; no extra registers)
        if (layer == 0 && t < kTT-1){
          #pragma unroll
          for (int kt = 0; kt < 2; ++kt)
            ax[u][kt] = *(const half8*)&xrow[u][(size_t)(t+1)*kHH + kt*32 + hi4*8];
        }
        if (t > 0){
          #pragma unroll
          for (int q = 0; q < 4; ++q){
            floatx4 a = acc[q];
            a = __builtin_amdgcn_mfma_f32_16x16x32_f16(ah[0], BH[q][0], a, 0,0,0);
            a = __builtin_amdgcn_mfma_f32_16x16x32_f16(ah[1], BH[q][1], a, 0,0,0);
            acc[q] = a;
          }
        }
        _Float16* hb = layer ? &h1b[u][t & 1][0] : &h0b[u][t & 1][0];
        #pragma unroll
        for (int r = 0; r < 4; ++r){
          float ii = sigf(acc[0][r]);
          float ff = sigf(acc[1][r]);
          float gt = tanh_fast(acc[2][r]);
          float oo = sigf(acc[3][r]);
          c[u][r] = ff*c[u][r] + ii*gt;
          float hn = oo * tanh_fast(c[u][r]);
          hb[(hi4*4 + r)*LP + wl*16 + lo] = (_Float16)hn;
        }
      }
    }
    __syncthreads();
  }
  // FC: h1(t=11) sits in h1b[u][1]; waves 4..4+kNU-1 handle tiles 0..kNU-1.
  if (w >= 4 && w < 4 + kNU){
    int u = w - 4;
    const _Float16* rb = &h1b[u][1][0];
    half8 a0 = *(const half8*)&rb[lo*LP + 0*32 + hi4*8];
    half8 a1 = *(const half8*)&rb[lo*LP + 1*32 + hi4*8];
    half8 F0, F1;
    const float* pf = fcw + (size_t)lo*kHH + hi4*8;
    #pragma unroll
    for (int j = 0; j < 8; ++j){ F0[j] = (_Float16)pf[j]; F1[j] = (_Float16)pf[32+j]; }
    floatx4 a = {0.f,0.f,0.f,0.f};
    a = __builtin_amdgcn_mfma_f32_16x16x32_f16(a0, F0, a, 0,0,0);
    a = __builtin_amdgcn_mfma_f32_16x16x32_f16(a1, F1, a, 0,0,0);
    float bo = fcb[lo];
    #pragma unroll
    for (int r = 0; r < 4; ++r){
      int n = nb0 + u*16 + hi4*4 + r;
      if (n < kNN) out[(size_t)n*kOUT + lo] = a[r] + bo;
    }
  }
}

extern "C" void kernel_launch(void* const* d_in, const int* in_sizes, int n_in,
                              void* d_out, int out_size, void* d_ws, size_t ws_size,
                              hipStream_t stream){
  const float* x    = (const float*)d_in[0];
  const int*   ei   = (const int*)  d_in[1];
  const float* gw0  = (const float*)d_in[2];
  const float* gb0  = (const float*)d_in[3];
  const float* gw1  = (const float*)d_in[4];
  const float* gb1  = (const float*)d_in[5];
  const float* wih0 = (const float*)d_in[6];
  const float* whh0 = (const float*)d_in[7];
  const float* bih0 = (const float*)d_in[8];
  const float* bhh0 = (const float*)d_in[9];
  const float* wih1 = (const float*)d_in[10];
  const float* whh1 = (const float*)d_in[11];
  const float* bih1 = (const float*)d_in[12];
  const float* bhh1 = (const float*)d_in[13];
  const float* fcw  = (const float*)d_in[14];
  const float* fcb  = (const float*)d_in[15];
  float* out = (float*)d_out;

  char* ws = (char*)d_ws;
  size_t p = 0;
  auto carve = [&](size_t bytes)->char*{
    char* r = ws + p;
    p += (bytes + 255) & ~(size_t)255;
    return r;
  };
  int*   cnt  = (int*)  carve(sizeof(int)*kNN);
  int*   cur  = (int*)  carve(sizeof(int)*kNN);
  int*   pb   = (int*)  carve(sizeof(int)*kPB);
  int*   offs = (int*)  carve(sizeof(int)*(kNN+1));
  float* dis  = (float*)carve(sizeof(float)*kNN);
  int2*  edat = (int2*) carve(sizeof(int2)*kNE);
  _Float16* xh   = (_Float16*)carve(sizeof(_Float16)*(size_t)kNN*kTT*kFIN); // 7.68MB
  _Float16* aggX = (_Float16*)carve(sizeof(_Float16)*(size_t)kNN*kTT*kFIN); // 7.68MB
  _Float16* bufA = (_Float16*)carve(sizeof(_Float16)*(size_t)kNN*kTT*kHH);  // 15.36MB
  _Float16* bufB = (_Float16*)carve(sizeof(_Float16)*(size_t)kNN*kTT*kHH);  // 15.36MB
  (void)ws_size; (void)in_sizes; (void)n_in; (void)out_size;

  // Whole CSR prologue + x-cast in ONE cooperative kernel (no memset needed:
  // cnt/cur zeroed in phase A, pb written unconditionally).
  {
    void* args[] = {(void*)&ei, (void*)&x, (void*)&xh, (void*)&cnt, (void*)&cur,
                    (void*)&offs, (void*)&dis, (void*)&edat, (void*)&pb};
    hipLaunchCooperativeKernel((const void*)k_prep, dim3(kPB), dim3(256),
                               args, 0, stream);
  }

  // GCN-0: aggregate 32-feat x first (A_hat x), then GEMM (+gb0+relu), t-major
  k_agg<kFIN><<<(kNN/2*(kTT/4) + 3)/4, 256, 0, stream>>>(xh, aggX, dis, offs, edat);
  k_gemm<kFIN, kHH, false><<<(kNN*kTT)/64, 256, 0, stream>>>(aggX, gw0, gb0, bufB);
  // GCN-1: aggregate 64-feat, GEMM (+gb1+relu) writes node-major for LSTM
  k_agg<kHH><<<(kNN/2*(kTT/2) + 3)/4, 256, 0, stream>>>(bufB, bufA, dis, offs, edat);
  k_gemm<kHH, kHH, true><<<(kNN*kTT)/64, 256, 0, stream>>>(bufA, gw1, gb1, bufB);

  // Fused 2-layer LSTM + FC -> out (three 16-node tiles per block)
  k_rec2<<<(kNN + 16*kNU - 1)/(16*kNU), 512, 0, stream>>>(bufB, wih0, whh0, bih0, bhh0,
                                          wih1, whh1, bih1, bhh1, fcw, fcb, out);
}

// Round 4
// 262.562 us; speedup vs baseline: 1.6309x; 1.6309x over previous
//
#include <hip/hip_runtime.h>
#include <hip/hip_bf16.h>

constexpr int kNN  = 10000;   // nodes
constexpr int kTT  = 12;      // timesteps
constexpr int kFIN = 32;      // input features
constexpr int kHH  = 64;      // hidden
constexpr int kH4  = 256;     // 4*hidden (gates)
constexpr int kOUT = 16;      // output features
constexpr int kNE  = 160000;  // edges

typedef _Float16 half8 __attribute__((ext_vector_type(8)));
typedef _Float16 half4 __attribute__((ext_vector_type(4)));
typedef _Float16 half2t __attribute__((ext_vector_type(2)));
typedef float floatx4 __attribute__((ext_vector_type(4)));

// Minimal-instruction activations (round-4): raw exp2 form, NO clamp needed —
// exp2(+inf)->inf, rcp(inf)->0 and exp2(-inf)->0 saturate both functions to
// the correct +-1 / {0,1} limits. sig: 4 VALU (mul,exp,add,rcp);
// tanh: 5 VALU (mul,exp,add,rcp,fma). Was ~8 each with IEEE-safe clamping.
__device__ __forceinline__ float rcp_fast(float x){ return __builtin_amdgcn_rcpf(x); }
__device__ __forceinline__ float sigf(float x){
  return rcp_fast(1.f + __builtin_amdgcn_exp2f(-1.44269504f*x));
}
__device__ __forceinline__ float tanh_fast(float x){
  return fmaf(-2.f, rcp_fast(__builtin_amdgcn_exp2f(2.88539008f*x) + 1.f), 1.f);
}

// int64-vs-int32 edge_index detection (odd words all zero <=> int64) fused
// with the x fp32 -> fp16 cast (independent elementwise work, saves a launch).
// (Round-3 cooperative fusion of the whole prologue REGRESSED: grid.sync()
// costs ~60us on MI355X — separate dispatches at ~3us/gap are far cheaper.)
__global__ void k_detect_cast(const int* __restrict__ ei, int* __restrict__ anyf,
                              const float* __restrict__ x, _Float16* __restrict__ xh){
  int a = 0;
  for (int i = blockIdx.x*256 + threadIdx.x; i < kNE; i += gridDim.x*256)
    a |= ei[2*i+1];
  unsigned long long m = __ballot(a != 0);
  if ((threadIdx.x & 63) == 0 && m) atomicOr(anyf, 1);
  const int NV = kNN*kTT*kFIN/4;
  for (int i = blockIdx.x*256 + threadIdx.x; i < NV; i += gridDim.x*256){
    float4 v = *(const float4*)&x[4*i];
    half4 h;
    h[0]=(_Float16)v.x; h[1]=(_Float16)v.y; h[2]=(_Float16)v.z; h[3]=(_Float16)v.w;
    *(half4*)&xh[4*i] = h;
  }
}

__global__ void k_deg(const int* __restrict__ ei, const int* __restrict__ anyf,
                      int* __restrict__ cnt){
  int e = blockIdx.x*256 + threadIdx.x;
  if (e >= kNE) return;
  int c = (anyf[0]==0) ? ei[2*(kNE+e)] : ei[kNE+e];
  atomicAdd(&cnt[c], 1);
}

// Exclusive scan of in-degree (single block, 1024 threads — this kernel runs
// on an otherwise idle machine, so per-thread serial chunk length matters:
// CH=10 instead of 40) + dis = rsqrt(deg+selfloop)
__global__ __launch_bounds__(1024) void k_scan(const int* __restrict__ cnt,
                       int* __restrict__ offs, float* __restrict__ dis){
  __shared__ int wsum[16];
  int tid = threadIdx.x;
  const int NT = 1024;
  const int CH = (kNN + NT - 1)/NT;
  int lo = tid*CH, hi = min(lo+CH, kNN);
  int s = 0;
  for (int i = lo; i < hi; ++i) s += cnt[i];
  int orig = s;
  int lane = tid & 63, wv = tid >> 6;
  #pragma unroll
  for (int d = 1; d < 64; d <<= 1){
    int v = __shfl_up(s, d, 64);
    if (lane >= d) s += v;
  }
  if (lane == 63) wsum[wv] = s;
  __syncthreads();
  int add = 0;
  for (int k2 = 0; k2 < wv; ++k2) add += wsum[k2];
  int run = s - orig + add;          // exclusive prefix for this thread's chunk
  for (int i = lo; i < hi; ++i){ offs[i] = run; run += cnt[i]; }
  if (hi == kNN) offs[kNN] = run;
  for (int i = tid; i < kNN; i += NT) dis[i] = rsqrtf((float)(cnt[i]+1));
}

// CSR scatter; packs (src, weight) into one int2 per edge (single scalar
// load per edge in k_agg).
__global__ void k_scatter(const int* __restrict__ ei, const int* __restrict__ anyf,
                          const int* __restrict__ offs, int* __restrict__ cur,
                          const float* __restrict__ dis,
                          int2* __restrict__ edat){
  int e = blockIdx.x*256 + threadIdx.x;
  if (e >= kNE) return;
  int f = (anyf[0]==0);
  int r = f ? ei[2*e]         : ei[e];
  int c = f ? ei[2*(kNE+e)]   : ei[kNE+e];
  int p = offs[c] + atomicAdd(&cur[c], 1);
  edat[p] = make_int2(r, __float_as_int(dis[r]*dis[c]));
}

// Pure GCN aggregation (no bias/relu — GEMM epilogue handles those since
// A_hat(xW) = (A_hat x)W). t-major in/out so each t-slab is L2-resident.
// Each wave walks TWO consecutive nodes with interleaved unroll-4 load
// batches: two independent latency chains per wave (the walk is
// latency-bound, ~16 L2-dependent edges/node), and half the wave count.
template<int F>
__global__ __launch_bounds__(256) void k_agg(const _Float16* __restrict__ hin,
                     _Float16* __restrict__ hout,
                     const float* __restrict__ dis,
                     const int* __restrict__ offs, const int2* __restrict__ edat){
  constexpr int LPF = F/2;            // lanes per timestep
  constexpr int TPW = 64/LPF;         // timesteps per wave
  constexpr int NP  = kNN/2;          // node pairs
  int wid = threadIdx.x >> 6, lane = threadIdx.x & 63;
  int gw = blockIdx.x*4 + wid;        // gw = tq*NP + np
  int tq = gw / NP, np = gw - tq*NP;
  int n0 = 2*np, n1 = n0 + 1;
  int fp = lane & (LPF-1), tsub = lane / LPF;
  int t = TPW*tq + tsub;
  const _Float16* hb = hin + (size_t)t*kNN*F;
  float dA = dis[n0], dB = dis[n1];
  half2t svA = *(const half2t*)&hb[(size_t)n0*F + 2*fp];
  half2t svB = *(const half2t*)&hb[(size_t)n1*F + 2*fp];
  float a0 = dA*dA*(float)svA[0], a1 = dA*dA*(float)svA[1];
  float b0 = dB*dB*(float)svB[0], b1 = dB*dB*(float)svB[1];
  int eA  = __builtin_amdgcn_readfirstlane(offs[n0]);
  int eM  = __builtin_amdgcn_readfirstlane(offs[n1]);
  int e1B = __builtin_amdgcn_readfirstlane(offs[n1+1]);
  int e1A = eM, eB = eM;
  // interleaved dual-chain unroll-4 (8 loads in flight per stage)
  while (eA + 4 <= e1A && eB + 4 <= e1B){
    int2 dA4[4], dB4[4];
    #pragma unroll
    for (int u = 0; u < 4; ++u) dA4[u] = edat[eA+u];
    #pragma unroll
    for (int u = 0; u < 4; ++u) dB4[u] = edat[eB+u];
    half2t vA[4], vB[4];
    #pragma unroll
    for (int u = 0; u < 4; ++u) vA[u] = *(const half2t*)&hb[(size_t)dA4[u].x*F + 2*fp];
    #pragma unroll
    for (int u = 0; u < 4; ++u) vB[u] = *(const half2t*)&hb[(size_t)dB4[u].x*F + 2*fp];
    #pragma unroll
    for (int u = 0; u < 4; ++u){
      float wA = __int_as_float(dA4[u].y), wB = __int_as_float(dB4[u].y);
      a0 = fmaf(wA, (float)vA[u][0], a0);
      a1 = fmaf(wA, (float)vA[u][1], a1);
      b0 = fmaf(wB, (float)vB[u][0], b0);
      b1 = fmaf(wB, (float)vB[u][1], b1);
    }
    eA += 4; eB += 4;
  }
  // drain A
  for (; eA + 4 <= e1A; eA += 4){
    int2 d4[4];
    #pragma unroll
    for (int u = 0; u < 4; ++u) d4[u] = edat[eA+u];
    half2t vv[4];
    #pragma unroll
    for (int u = 0; u < 4; ++u) vv[u] = *(const half2t*)&hb[(size_t)d4[u].x*F + 2*fp];
    #pragma unroll
    for (int u = 0; u < 4; ++u){
      float wu = __int_as_float(d4[u].y);
      a0 = fmaf(wu, (float)vv[u][0], a0);
      a1 = fmaf(wu, (float)vv[u][1], a1);
    }
  }
  for (; eA < e1A; ++eA){
    int2 du = edat[eA];
    float wu = __int_as_float(du.y);
    half2t vu = *(const half2t*)&hb[(size_t)du.x*F + 2*fp];
    a0 = fmaf(wu, (float)vu[0], a0);
    a1 = fmaf(wu, (float)vu[1], a1);
  }
  // drain B
  for (; eB + 4 <= e1B; eB += 4){
    int2 d4[4];
    #pragma unroll
    for (int u = 0; u < 4; ++u) d4[u] = edat[eB+u];
    half2t vv[4];
    #pragma unroll
    for (int u = 0; u < 4; ++u) vv[u] = *(const half2t*)&hb[(size_t)d4[u].x*F + 2*fp];
    #pragma unroll
    for (int u = 0; u < 4; ++u){
      float wu = __int_as_float(d4[u].y);
      b0 = fmaf(wu, (float)vv[u][0], b0);
      b1 = fmaf(wu, (float)vv[u][1], b1);
    }
  }
  for (; eB < e1B; ++eB){
    int2 du = edat[eB];
    float wu = __int_as_float(du.y);
    half2t vu = *(const half2t*)&hb[(size_t)du.x*F + 2*fp];
    b0 = fmaf(wu, (float)vu[0], b0);
    b1 = fmaf(wu, (float)vu[1], b1);
  }
  half2t oA; oA[0] = (_Float16)a0; oA[1] = (_Float16)a1;
  *(half2t*)&hout[((size_t)t*kNN + n0)*F + 2*fp] = oA;
  half2t oB; oB[0] = (_Float16)b0; oB[1] = (_Float16)b1;
  *(half2t*)&hout[((size_t)t*kNN + n1)*F + 2*fp] = oB;
}

// Tiled GEMM: out[M,N] = relu(in[M,K] @ W[K,N] + bias), fp16 in/out, fp32 acc.
// Rows m are t-major (m = t*kNN + n). NM: store node-major ((n*T+t)*N).
template<int K, int N, bool NM>
__global__ __launch_bounds__(256) void k_gemm(const _Float16* __restrict__ in,
                      const float* __restrict__ Wg, const float* __restrict__ bias,
                      _Float16* __restrict__ out){
  constexpr int COLG = N/4;
  constexpr int ROWG = 256/COLG;
  constexpr int MR   = 4;
  constexpr int MTILE= ROWG*MR;       // 64
  constexpr int AP   = K + 4;
  __shared__ float Wl[K*N];
  __shared__ float Al[MTILE*AP];
  int tid = threadIdx.x;
  int m0 = blockIdx.x*MTILE;
  for (int idx = tid; idx < MTILE*K/8; idx += 256){
    int r = idx/(K/8), k8 = idx - r*(K/8);
    half8 v = *(const half8*)&in[(size_t)(m0 + r)*K + k8*8];
    float* dst = &Al[r*AP + k8*8];
    #pragma unroll
    for (int j = 0; j < 8; ++j) dst[j] = (float)v[j];
  }
  for (int idx = tid; idx < K*N; idx += 256) Wl[idx] = Wg[idx];
  __syncthreads();
  int cg = tid % COLG, rg = tid / COLG;
  int c0 = cg*4, r0 = rg*MR;
  float acc[MR][4];
  #pragma unroll
  for (int r=0;r<MR;++r){acc[r][0]=0.f;acc[r][1]=0.f;acc[r][2]=0.f;acc[r][3]=0.f;}
  #pragma unroll 2
  for (int k = 0; k < K; k += 4){
    float4 wv[4];
    #pragma unroll
    for (int kk = 0; kk < 4; ++kk) wv[kk] = *(const float4*)&Wl[(k+kk)*N + c0];
    #pragma unroll
    for (int r = 0; r < MR; ++r){
      float4 a4 = *(const float4*)&Al[(r0+r)*AP + k];
      acc[r][0] = fmaf(a4.x, wv[0].x, acc[r][0]);
      acc[r][1] = fmaf(a4.x, wv[0].y, acc[r][1]);
      acc[r][2] = fmaf(a4.x, wv[0].z, acc[r][2]);
      acc[r][3] = fmaf(a4.x, wv[0].w, acc[r][3]);
      acc[r][0] = fmaf(a4.y, wv[1].x, acc[r][0]);
      acc[r][1] = fmaf(a4.y, wv[1].y, acc[r][1]);
      acc[r][2] = fmaf(a4.y, wv[1].z, acc[r][2]);
      acc[r][3] = fmaf(a4.y, wv[1].w, acc[r][3]);
      acc[r][0] = fmaf(a4.z, wv[2].x, acc[r][0]);
      acc[r][1] = fmaf(a4.z, wv[2].y, acc[r][1]);
      acc[r][2] = fmaf(a4.z, wv[2].z, acc[r][2]);
      acc[r][3] = fmaf(a4.z, wv[2].w, acc[r][3]);
      acc[r][0] = fmaf(a4.w, wv[3].x, acc[r][0]);
      acc[r][1] = fmaf(a4.w, wv[3].y, acc[r][1]);
      acc[r][2] = fmaf(a4.w, wv[3].z, acc[r][2]);
      acc[r][3] = fmaf(a4.w, wv[3].w, acc[r][3]);
    }
  }
  float4 bb = *(const float4*)&bias[c0];
  #pragma unroll
  for (int r = 0; r < MR; ++r){
    half4 hv;
    hv[0]=(_Float16)fmaxf(acc[r][0]+bb.x, 0.f);
    hv[1]=(_Float16)fmaxf(acc[r][1]+bb.y, 0.f);
    hv[2]=(_Float16)fmaxf(acc[r][2]+bb.z, 0.f);
    hv[3]=(_Float16)fmaxf(acc[r][3]+bb.w, 0.f);
    int m = m0 + r0 + r;
    size_t oi;
    if (NM){ int t = m/kNN, n = m - t*kNN; oi = ((size_t)n*kTT + t)*N + c0; }
    else    oi = (size_t)m*N + c0;
    *(half4*)&out[oi] = hv;
  }
}

// Fused 2-layer LSTM + FC, THREE 16-node tiles per block (48 nodes).
// Block = 512 thr = 8 waves; waves 0-3 layer0, 4-7 layer1 one t behind,
// h exchanged through per-tile double-buffered LDS.
// launch_bounds(512,2): full 256-reg budget, NO spill; grid 209 <= 256 CUs
// runs in one dispatch round (round-2 verified: 44.5us, VGPR=92).
constexpr int kNU = 3;                         // tiles per block
__global__ __launch_bounds__(512, 2) void k_rec2(const _Float16* __restrict__ xin,
                     const float* __restrict__ wih0, const float* __restrict__ whh0,
                     const float* __restrict__ bih0, const float* __restrict__ bhh0,
                     const float* __restrict__ wih1, const float* __restrict__ whh1,
                     const float* __restrict__ bih1, const float* __restrict__ bhh1,
                     const float* __restrict__ fcw, const float* __restrict__ fcb,
                     float* __restrict__ out){
  constexpr int LP = 72;                       // LDS row pitch (halves)
  __shared__ _Float16 h0b[kNU][2][16*LP];      // [tile][dbuf]
  __shared__ _Float16 h1b[kNU][2][16*LP];
  int tid = threadIdx.x, w = tid >> 6, lane = tid & 63;
  int lo = lane & 15, hi4 = lane >> 4;
  int layer = w >> 2, wl = w & 3;
  int nb0 = blockIdx.x*(16*kNU);

  const float* wih = layer ? wih1 : wih0;
  const float* whh = layer ? whh1 : whh0;
  const float* bi_ = layer ? bih1 : bih0;
  const float* bh_ = layer ? bhh1 : bhh0;

  half8 BI[4][2], BH[4][2];
  #pragma unroll
  for (int q = 0; q < 4; ++q){
    int row = q*kHH + wl*16 + lo;
    #pragma unroll
    for (int kt = 0; kt < 2; ++kt){
      const float* pi = wih + (size_t)row*kHH + kt*32 + hi4*8;
      const float* ph = whh + (size_t)row*kHH + kt*32 + hi4*8;
      half8 fi, fh;
      #pragma unroll
      for (int j = 0; j < 8; ++j){ fi[j] = (_Float16)pi[j]; fh[j] = (_Float16)ph[j]; }
      BI[q][kt] = fi; BH[q][kt] = fh;
    }
  }
  float bias[4];
  #pragma unroll
  for (int q = 0; q < 4; ++q){
    int col = q*kHH + wl*16 + lo;
    bias[q] = bi_[col] + bh_[col];
  }

  float c[kNU][4];
  #pragma unroll
  for (int u = 0; u < kNU; ++u){c[u][0]=0.f;c[u][1]=0.f;c[u][2]=0.f;c[u][3]=0.f;}
  half8 ax[kNU][2];

  const _Float16* xrow[kNU];
  #pragma unroll
  for (int u = 0; u < kNU; ++u)
    xrow[u] = xin + (size_t)min(nb0 + u*16 + lo, kNN-1)*kTT*kHH;
  if (layer == 0){
    #pragma unroll
    for (int u = 0; u < kNU; ++u)
      #pragma unroll
      for (int kt = 0; kt < 2; ++kt)
        ax[u][kt] = *(const half8*)&xrow[u][kt*32 + hi4*8];
  }

  for (int i = 0; i < 13; ++i){
    int t = layer ? i-1 : i;
    bool act = layer ? (i >= 1) : (i < 12);
    if (act){
      #pragma unroll
      for (int u = 0; u < kNU; ++u){
        // layer1 input = h0(t), written by layer0 in iter i-1 (buf t&1);
        // layer0 this iter writes buf (t+1)&1 -> no race.
        if (layer){
          const _Float16* rb = &h0b[u][t & 1][0];
          #pragma unroll
          for (int kt = 0; kt < 2; ++kt)
            ax[u][kt] = *(const half8*)&rb[lo*LP + kt*32 + hi4*8];
        }
        half8 ah[2];
        if (t > 0){
          // recurrent h(t-1): buf (t-1)&1, written iter i-1; this iter writes
          // buf t&1 -> no race.
          const _Float16* rb = layer ? &h1b[u][(t-1) & 1][0] : &h0b[u][(t-1) & 1][0];
          #pragma unroll
          for (int kt = 0; kt < 2; ++kt)
            ah[kt] = *(const half8*)&rb[lo*LP + kt*32 + hi4*8];
        }
        floatx4 acc[4];
        #pragma unroll
        for (int q = 0; q < 4; ++q){
          floatx4 a = {bias[q], bias[q], bias[q], bias[q]};
          a = __builtin_amdgcn_mfma_f32_16x16x32_f16(ax[u][0], BI[q][0], a, 0,0,0);
          a = __builtin_amdgcn_mfma_f32_16x16x32_f16(ax[u][1], BI[q][1], a, 0,0,0);
          acc[q] = a;
        }
        // prefetch next-t x into the just-consumed ax regs (overlaps h-MFMA +
        // epilogue + barrier; no extra registers)
        if (layer == 0 && t < kTT-1){
          #pragma unroll
          for (int kt = 0; kt < 2; ++kt)
            ax[u][kt] = *(const half8*)&xrow[u][(size_t)(t+1)*kHH + kt*32 + hi4*8];
        }
        if (t > 0){
          #pragma unroll
          for (int q = 0; q < 4; ++q){
            floatx4 a = acc[q];
            a = __builtin_amdgcn_mfma_f32_16x16x32_f16(ah[0], BH[q][0], a, 0,0,0);
            a = __builtin_amdgcn_mfma_f32_16x16x32_f16(ah[1], BH[q][1], a, 0,0,0);
            acc[q] = a;
          }
        }
        _Float16* hb = layer ? &h1b[u][t & 1][0] : &h0b[u][t & 1][0];
        #pragma unroll
        for (int r = 0; r < 4; ++r){
          float ii = sigf(acc[0][r]);
          float ff = sigf(acc[1][r]);
          float gt = tanh_fast(acc[2][r]);
          float oo = sigf(acc[3][r]);
          c[u][r] = ff*c[u][r] + ii*gt;
          float hn = oo * tanh_fast(c[u][r]);
          hb[(hi4*4 + r)*LP + wl*16 + lo] = (_Float16)hn;
        }
      }
    }
    __syncthreads();
  }
  // FC: h1(t=11) sits in h1b[u][1]; waves 4..4+kNU-1 handle tiles 0..kNU-1.
  if (w >= 4 && w < 4 + kNU){
    int u = w - 4;
    const _Float16* rb = &h1b[u][1][0];
    half8 a0 = *(const half8*)&rb[lo*LP + 0*32 + hi4*8];
    half8 a1 = *(const half8*)&rb[lo*LP + 1*32 + hi4*8];
    half8 F0, F1;
    const float* pf = fcw + (size_t)lo*kHH + hi4*8;
    #pragma unroll
    for (int j = 0; j < 8; ++j){ F0[j] = (_Float16)pf[j]; F1[j] = (_Float16)pf[32+j]; }
    floatx4 a = {0.f,0.f,0.f,0.f};
    a = __builtin_amdgcn_mfma_f32_16x16x32_f16(a0, F0, a, 0,0,0);
    a = __builtin_amdgcn_mfma_f32_16x16x32_f16(a1, F1, a, 0,0,0);
    float bo = fcb[lo];
    #pragma unroll
    for (int r = 0; r < 4; ++r){
      int n = nb0 + u*16 + hi4*4 + r;
      if (n < kNN) out[(size_t)n*kOUT + lo] = a[r] + bo;
    }
  }
}

extern "C" void kernel_launch(void* const* d_in, const int* in_sizes, int n_in,
                              void* d_out, int out_size, void* d_ws, size_t ws_size,
                              hipStream_t stream){
  const float* x    = (const float*)d_in[0];
  const int*   ei   = (const int*)  d_in[1];
  const float* gw0  = (const float*)d_in[2];
  const float* gb0  = (const float*)d_in[3];
  const float* gw1  = (const float*)d_in[4];
  const float* gb1  = (const float*)d_in[5];
  const float* wih0 = (const float*)d_in[6];
  const float* whh0 = (const float*)d_in[7];
  const float* bih0 = (const float*)d_in[8];
  const float* bhh0 = (const float*)d_in[9];
  const float* wih1 = (const float*)d_in[10];
  const float* whh1 = (const float*)d_in[11];
  const float* bih1 = (const float*)d_in[12];
  const float* bhh1 = (const float*)d_in[13];
  const float* fcw  = (const float*)d_in[14];
  const float* fcb  = (const float*)d_in[15];
  float* out = (float*)d_out;

  char* ws = (char*)d_ws;
  size_t p = 0;
  auto carve = [&](size_t bytes)->char*{
    char* r = ws + p;
    p += (bytes + 255) & ~(size_t)255;
    return r;
  };
  // anyf, cnt, cur contiguous -> single memset
  int*   anyf = (int*)  carve(256);
  int*   cnt  = (int*)  carve(sizeof(int)*kNN);
  int*   cur  = (int*)  carve(sizeof(int)*kNN);
  size_t zbytes = p;
  int*   offs = (int*)  carve(sizeof(int)*(kNN+1));
  float* dis  = (float*)carve(sizeof(float)*kNN);
  int2*  edat = (int2*) carve(sizeof(int2)*kNE);
  _Float16* xh   = (_Float16*)carve(sizeof(_Float16)*(size_t)kNN*kTT*kFIN); // 7.68MB
  _Float16* aggX = (_Float16*)carve(sizeof(_Float16)*(size_t)kNN*kTT*kFIN); // 7.68MB
  _Float16* bufA = (_Float16*)carve(sizeof(_Float16)*(size_t)kNN*kTT*kHH);  // 15.36MB
  _Float16* bufB = (_Float16*)carve(sizeof(_Float16)*(size_t)kNN*kTT*kHH);  // 15.36MB
  (void)ws_size; (void)in_sizes; (void)n_in; (void)out_size;

  hipMemsetAsync(ws, 0, zbytes, stream);
  k_detect_cast<<<440, 256, 0, stream>>>(ei, anyf, x, xh);
  k_deg    <<<(kNE+255)/256, 256, 0, stream>>>(ei, anyf, cnt);
  k_scan   <<<1, 1024, 0, stream>>>(cnt, offs, dis);
  k_scatter<<<(kNE+255)/256, 256, 0, stream>>>(ei, anyf, offs, cur, dis, edat);

  // GCN-0: aggregate 32-feat x first (A_hat x), then GEMM (+gb0+relu), t-major
  k_agg<kFIN><<<(kNN/2*(kTT/4) + 3)/4, 256, 0, stream>>>(xh, aggX, dis, offs, edat);
  k_gemm<kFIN, kHH, false><<<(kNN*kTT)/64, 256, 0, stream>>>(aggX, gw0, gb0, bufB);
  // GCN-1: aggregate 64-feat, GEMM (+gb1+relu) writes node-major for LSTM
  k_agg<kHH><<<(kNN/2*(kTT/2) + 3)/4, 256, 0, stream>>>(bufB, bufA, dis, offs, edat);
  k_gemm<kHH, kHH, true><<<(kNN*kTT)/64, 256, 0, stream>>>(bufA, gw1, gb1, bufB);

  // Fused 2-layer LSTM + FC -> out (three 16-node tiles per block)
  k_rec2<<<(kNN + 16*kNU - 1)/(16*kNU), 512, 0, stream>>>(bufB, wih0, whh0, bih0, bhh0,
                                          wih1, whh1, bih1, bhh1, fcw, fcb, out);
}

// Round 5
// 251.196 us; speedup vs baseline: 1.7047x; 1.0452x over previous
//
#include <hip/hip_runtime.h>
#include <hip/hip_bf16.h>

constexpr int kNN  = 10000;   // nodes
constexpr int kTT  = 12;      // timesteps
constexpr int kFIN = 32;      // input features
constexpr int kHH  = 64;      // hidden
constexpr int kH4  = 256;     // 4*hidden (gates)
constexpr int kOUT = 16;      // output features
constexpr int kNE  = 160000;  // edges
constexpr int kDB  = 256;     // detect blocks (pb[] partials)

typedef _Float16 half8 __attribute__((ext_vector_type(8)));
typedef _Float16 half4 __attribute__((ext_vector_type(4)));
typedef _Float16 half2t __attribute__((ext_vector_type(2)));
typedef float floatx4 __attribute__((ext_vector_type(4)));

// Minimal-instruction activations: raw exp2 form, NO clamp needed —
// exp2(+inf)->inf, rcp(inf)->0 and exp2(-inf)->0 saturate both functions to
// the correct +-1 / {0,1} limits. sig: 4 VALU; tanh: 5 VALU.
__device__ __forceinline__ float rcp_fast(float x){ return __builtin_amdgcn_rcpf(x); }
__device__ __forceinline__ float sigf(float x){
  return rcp_fast(1.f + __builtin_amdgcn_exp2f(-1.44269504f*x));
}
__device__ __forceinline__ float tanh_fast(float x){
  return fmaf(-2.f, rcp_fast(__builtin_amdgcn_exp2f(2.88539008f*x) + 1.f), 1.f);
}

// Typed 2-element gather load -> float2 (lets k_agg read fp32 x directly:
// the separate x fp32->fp16 cast kernel is deleted; per-t slab is L2-resident
// and the edge walk is latency-bound, so 2x gather bytes are ~free).
__device__ __forceinline__ float2 ld2f(const _Float16* p){
  half2t h = *(const half2t*)p; return make_float2((float)h[0], (float)h[1]);
}
__device__ __forceinline__ float2 ld2f(const float* p){
  return *(const float2*)p;
}

// int64-vs-int32 edge_index detection (odd words all zero <=> int64).
// Writes per-block partials pb[bid] UNCONDITIONALLY (no zero-init needed —
// workspace arrives poisoned). Also zeroes cnt (replaces hipMemsetAsync).
// (Round-3 lesson: grid.sync() costs ~60us on MI355X — keep separate
// dispatches, ~3us/gap.)
__global__ void k_detect_zero(const int* __restrict__ ei, int* __restrict__ pb,
                              int* __restrict__ cnt){
  int a = 0;
  for (int i = blockIdx.x*256 + threadIdx.x; i < kNE; i += gridDim.x*256)
    a |= ei[2*i+1];
  unsigned long long m = __ballot(a != 0);
  if ((threadIdx.x & 63) == 0) (void)0;
  __shared__ int bf;
  if (threadIdx.x == 0) bf = 0;
  __syncthreads();
  if (m && (threadIdx.x & 63) == 0) atomicOr(&bf, 1);
  __syncthreads();
  if (threadIdx.x == 0) pb[blockIdx.x] = bf;
  for (int i = blockIdx.x*256 + threadIdx.x; i < kNN; i += gridDim.x*256)
    cnt[i] = 0;
}

// Reduce pb[] -> per-block uniform is64 flag (256 L2-hot loads + 2 barriers).
__device__ __forceinline__ bool reduce_is64(const int* __restrict__ pb, int* sflag){
  int v = 0;
  for (int i = threadIdx.x; i < kDB; i += 256) v |= pb[i];
  if (threadIdx.x == 0) *sflag = 0;
  __syncthreads();
  if (v) atomicOr(sflag, 1);
  __syncthreads();
  return (*sflag == 0);            // odd words all zero <=> int64 input
}

__global__ void k_deg(const int* __restrict__ ei, const int* __restrict__ pb,
                      int* __restrict__ cnt){
  __shared__ int sflag;
  bool is64 = reduce_is64(pb, &sflag);
  int e = blockIdx.x*256 + threadIdx.x;
  if (e >= kNE) return;
  int c = is64 ? ei[2*(kNE+e)] : ei[kNE+e];
  atomicAdd(&cnt[c], 1);
}

// Exclusive scan of in-degree (single block, 1024 threads) + dis =
// rsqrt(deg+selfloop) + cur initialized to offs (scatter mutates cur only).
__global__ __launch_bounds__(1024) void k_scan(const int* __restrict__ cnt,
                       int* __restrict__ offs, int* __restrict__ cur,
                       float* __restrict__ dis){
  __shared__ int wsum[16];
  int tid = threadIdx.x;
  const int NT = 1024;
  const int CH = (kNN + NT - 1)/NT;
  int lo = tid*CH, hi = min(lo+CH, kNN);
  int s = 0;
  for (int i = lo; i < hi; ++i) s += cnt[i];
  int orig = s;
  int lane = tid & 63, wv = tid >> 6;
  #pragma unroll
  for (int d = 1; d < 64; d <<= 1){
    int v = __shfl_up(s, d, 64);
    if (lane >= d) s += v;
  }
  if (lane == 63) wsum[wv] = s;
  __syncthreads();
  int add = 0;
  for (int k2 = 0; k2 < wv; ++k2) add += wsum[k2];
  int run = s - orig + add;          // exclusive prefix for this thread's chunk
  for (int i = lo; i < hi; ++i){ offs[i] = run; cur[i] = run; run += cnt[i]; }
  if (hi == kNN) offs[kNN] = run;
  for (int i = tid; i < kNN; i += NT) dis[i] = rsqrtf((float)(cnt[i]+1));
}

// CSR scatter; packs (src, weight) into one int2 per edge. Slot comes
// straight from atomicAdd on cur (pre-initialized to offs by k_scan).
__global__ void k_scatter(const int* __restrict__ ei, const int* __restrict__ pb,
                          int* __restrict__ cur, const float* __restrict__ dis,
                          int2* __restrict__ edat){
  __shared__ int sflag;
  bool is64 = reduce_is64(pb, &sflag);
  int e = blockIdx.x*256 + threadIdx.x;
  if (e >= kNE) return;
  int r = is64 ? ei[2*e]       : ei[e];
  int c = is64 ? ei[2*(kNE+e)] : ei[kNE+e];
  int p = atomicAdd(&cur[c], 1);
  edat[p] = make_int2(r, __float_as_int(dis[r]*dis[c]));
}

// Pure GCN aggregation (no bias/relu — GEMM epilogue handles those since
// A_hat(xW) = (A_hat x)W). t-major in/out so each t-slab is L2-resident.
// TIN templated: first layer gathers directly from fp32 x (no cast pass).
// Each wave walks TWO consecutive nodes with interleaved unroll-4 load
// batches: two independent latency chains per wave.
template<int F, typename TIN>
__global__ __launch_bounds__(256) void k_agg(const TIN* __restrict__ hin,
                     _Float16* __restrict__ hout,
                     const float* __restrict__ dis,
                     const int* __restrict__ offs, const int2* __restrict__ edat){
  constexpr int LPF = F/2;            // lanes per timestep
  constexpr int TPW = 64/LPF;         // timesteps per wave
  constexpr int NP  = kNN/2;          // node pairs
  int wid = threadIdx.x >> 6, lane = threadIdx.x & 63;
  int gw = blockIdx.x*4 + wid;        // gw = tq*NP + np
  int tq = gw / NP, np = gw - tq*NP;
  int n0 = 2*np, n1 = n0 + 1;
  int fp = lane & (LPF-1), tsub = lane / LPF;
  int t = TPW*tq + tsub;
  const TIN* hb = hin + (size_t)t*kNN*F;
  float dA = dis[n0], dB = dis[n1];
  float2 svA = ld2f(&hb[(size_t)n0*F + 2*fp]);
  float2 svB = ld2f(&hb[(size_t)n1*F + 2*fp]);
  float a0 = dA*dA*svA.x, a1 = dA*dA*svA.y;
  float b0 = dB*dB*svB.x, b1 = dB*dB*svB.y;
  int eA  = __builtin_amdgcn_readfirstlane(offs[n0]);
  int eM  = __builtin_amdgcn_readfirstlane(offs[n1]);
  int e1B = __builtin_amdgcn_readfirstlane(offs[n1+1]);
  int e1A = eM, eB = eM;
  // interleaved dual-chain unroll-4 (8 loads in flight per stage)
  while (eA + 4 <= e1A && eB + 4 <= e1B){
    int2 dA4[4], dB4[4];
    #pragma unroll
    for (int u = 0; u < 4; ++u) dA4[u] = edat[eA+u];
    #pragma unroll
    for (int u = 0; u < 4; ++u) dB4[u] = edat[eB+u];
    float2 vA[4], vB[4];
    #pragma unroll
    for (int u = 0; u < 4; ++u) vA[u] = ld2f(&hb[(size_t)dA4[u].x*F + 2*fp]);
    #pragma unroll
    for (int u = 0; u < 4; ++u) vB[u] = ld2f(&hb[(size_t)dB4[u].x*F + 2*fp]);
    #pragma unroll
    for (int u = 0; u < 4; ++u){
      float wA = __int_as_float(dA4[u].y), wB = __int_as_float(dB4[u].y);
      a0 = fmaf(wA, vA[u].x, a0);
      a1 = fmaf(wA, vA[u].y, a1);
      b0 = fmaf(wB, vB[u].x, b0);
      b1 = fmaf(wB, vB[u].y, b1);
    }
    eA += 4; eB += 4;
  }
  // drain A
  for (; eA + 4 <= e1A; eA += 4){
    int2 d4[4];
    #pragma unroll
    for (int u = 0; u < 4; ++u) d4[u] = edat[eA+u];
    float2 vv[4];
    #pragma unroll
    for (int u = 0; u < 4; ++u) vv[u] = ld2f(&hb[(size_t)d4[u].x*F + 2*fp]);
    #pragma unroll
    for (int u = 0; u < 4; ++u){
      float wu = __int_as_float(d4[u].y);
      a0 = fmaf(wu, vv[u].x, a0);
      a1 = fmaf(wu, vv[u].y, a1);
    }
  }
  for (; eA < e1A; ++eA){
    int2 du = edat[eA];
    float wu = __int_as_float(du.y);
    float2 vu = ld2f(&hb[(size_t)du.x*F + 2*fp]);
    a0 = fmaf(wu, vu.x, a0);
    a1 = fmaf(wu, vu.y, a1);
  }
  // drain B
  for (; eB + 4 <= e1B; eB += 4){
    int2 d4[4];
    #pragma unroll
    for (int u = 0; u < 4; ++u) d4[u] = edat[eB+u];
    float2 vv[4];
    #pragma unroll
    for (int u = 0; u < 4; ++u) vv[u] = ld2f(&hb[(size_t)d4[u].x*F + 2*fp]);
    #pragma unroll
    for (int u = 0; u < 4; ++u){
      float wu = __int_as_float(d4[u].y);
      b0 = fmaf(wu, vv[u].x, b0);
      b1 = fmaf(wu, vv[u].y, b1);
    }
  }
  for (; eB < e1B; ++eB){
    int2 du = edat[eB];
    float wu = __int_as_float(du.y);
    float2 vu = ld2f(&hb[(size_t)du.x*F + 2*fp]);
    b0 = fmaf(wu, vu.x, b0);
    b1 = fmaf(wu, vu.y, b1);
  }
  half2t oA; oA[0] = (_Float16)a0; oA[1] = (_Float16)a1;
  *(half2t*)&hout[((size_t)t*kNN + n0)*F + 2*fp] = oA;
  half2t oB; oB[0] = (_Float16)b0; oB[1] = (_Float16)b1;
  *(half2t*)&hout[((size_t)t*kNN + n1)*F + 2*fp] = oB;
}

// Tiled GEMM: out[M,N] = relu(in[M,K] @ W[K,N] + bias), fp16 in/out, fp32 acc.
// Rows m are t-major (m = t*kNN + n). NM: store node-major ((n*T+t)*N).
template<int K, int N, bool NM>
__global__ __launch_bounds__(256) void k_gemm(const _Float16* __restrict__ in,
                      const float* __restrict__ Wg, const float* __restrict__ bias,
                      _Float16* __restrict__ out){
  constexpr int COLG = N/4;
  constexpr int ROWG = 256/COLG;
  constexpr int MR   = 4;
  constexpr int MTILE= ROWG*MR;       // 64
  constexpr int AP   = K + 4;
  __shared__ float Wl[K*N];
  __shared__ float Al[MTILE*AP];
  int tid = threadIdx.x;
  int m0 = blockIdx.x*MTILE;
  for (int idx = tid; idx < MTILE*K/8; idx += 256){
    int r = idx/(K/8), k8 = idx - r*(K/8);
    half8 v = *(const half8*)&in[(size_t)(m0 + r)*K + k8*8];
    float* dst = &Al[r*AP + k8*8];
    #pragma unroll
    for (int j = 0; j < 8; ++j) dst[j] = (float)v[j];
  }
  for (int idx = tid; idx < K*N; idx += 256) Wl[idx] = Wg[idx];
  __syncthreads();
  int cg = tid % COLG, rg = tid / COLG;
  int c0 = cg*4, r0 = rg*MR;
  float acc[MR][4];
  #pragma unroll
  for (int r=0;r<MR;++r){acc[r][0]=0.f;acc[r][1]=0.f;acc[r][2]=0.f;acc[r][3]=0.f;}
  #pragma unroll 2
  for (int k = 0; k < K; k += 4){
    float4 wv[4];
    #pragma unroll
    for (int kk = 0; kk < 4; ++kk) wv[kk] = *(const float4*)&Wl[(k+kk)*N + c0];
    #pragma unroll
    for (int r = 0; r < MR; ++r){
      float4 a4 = *(const float4*)&Al[(r0+r)*AP + k];
      acc[r][0] = fmaf(a4.x, wv[0].x, acc[r][0]);
      acc[r][1] = fmaf(a4.x, wv[0].y, acc[r][1]);
      acc[r][2] = fmaf(a4.x, wv[0].z, acc[r][2]);
      acc[r][3] = fmaf(a4.x, wv[0].w, acc[r][3]);
      acc[r][0] = fmaf(a4.y, wv[1].x, acc[r][0]);
      acc[r][1] = fmaf(a4.y, wv[1].y, acc[r][1]);
      acc[r][2] = fmaf(a4.y, wv[1].z, acc[r][2]);
      acc[r][3] = fmaf(a4.y, wv[1].w, acc[r][3]);
      acc[r][0] = fmaf(a4.z, wv[2].x, acc[r][0]);
      acc[r][1] = fmaf(a4.z, wv[2].y, acc[r][1]);
      acc[r][2] = fmaf(a4.z, wv[2].z, acc[r][2]);
      acc[r][3] = fmaf(a4.z, wv[2].w, acc[r][3]);
      acc[r][0] = fmaf(a4.w, wv[3].x, acc[r][0]);
      acc[r][1] = fmaf(a4.w, wv[3].y, acc[r][1]);
      acc[r][2] = fmaf(a4.w, wv[3].z, acc[r][2]);
      acc[r][3] = fmaf(a4.w, wv[3].w, acc[r][3]);
    }
  }
  float4 bb = *(const float4*)&bias[c0];
  #pragma unroll
  for (int r = 0; r < MR; ++r){
    half4 hv;
    hv[0]=(_Float16)fmaxf(acc[r][0]+bb.x, 0.f);
    hv[1]=(_Float16)fmaxf(acc[r][1]+bb.y, 0.f);
    hv[2]=(_Float16)fmaxf(acc[r][2]+bb.z, 0.f);
    hv[3]=(_Float16)fmaxf(acc[r][3]+bb.w, 0.f);
    int m = m0 + r0 + r;
    size_t oi;
    if (NM){ int t = m/kNN, n = m - t*kNN; oi = ((size_t)n*kTT + t)*N + c0; }
    else    oi = (size_t)m*N + c0;
    *(half4*)&out[oi] = hv;
  }
}

// Fused 2-layer LSTM + FC, THREE 16-node tiles per block (48 nodes).
// Block = 512 thr = 8 waves; waves 0-3 layer0, 4-7 layer1 one t behind,
// h exchanged through per-tile double-buffered LDS.
// launch_bounds(512,2): full 256-reg budget, NO spill; grid 209 <= 256 CUs
// runs in one dispatch round.
// axn prefetch double-buffer (reinstated): next-t x loads are issued at the
// TOP of the step so the __syncthreads vmcnt(0) drain at step end never
// exposes HBM latency (bufB is 15.4MB > 4MB/XCD L2 -> ~900cy misses).
constexpr int kNU = 3;                         // tiles per block
__global__ __launch_bounds__(512, 2) void k_rec2(const _Float16* __restrict__ xin,
                     const float* __restrict__ wih0, const float* __restrict__ whh0,
                     const float* __restrict__ bih0, const float* __restrict__ bhh0,
                     const float* __restrict__ wih1, const float* __restrict__ whh1,
                     const float* __restrict__ bih1, const float* __restrict__ bhh1,
                     const float* __restrict__ fcw, const float* __restrict__ fcb,
                     float* __restrict__ out){
  constexpr int LP = 72;                       // LDS row pitch (halves)
  __shared__ _Float16 h0b[kNU][2][16*LP];      // [tile][dbuf]
  __shared__ _Float16 h1b[kNU][2][16*LP];
  int tid = threadIdx.x, w = tid >> 6, lane = tid & 63;
  int lo = lane & 15, hi4 = lane >> 4;
  int layer = w >> 2, wl = w & 3;
  int nb0 = blockIdx.x*(16*kNU);

  const float* wih = layer ? wih1 : wih0;
  const float* whh = layer ? whh1 : whh0;
  const float* bi_ = layer ? bih1 : bih0;
  const float* bh_ = layer ? bhh1 : bhh0;

  half8 BI[4][2], BH[4][2];
  #pragma unroll
  for (int q = 0; q < 4; ++q){
    int row = q*kHH + wl*16 + lo;
    #pragma unroll
    for (int kt = 0; kt < 2; ++kt){
      const float* pi = wih + (size_t)row*kHH + kt*32 + hi4*8;
      const float* ph = whh + (size_t)row*kHH + kt*32 + hi4*8;
      half8 fi, fh;
      #pragma unroll
      for (int j = 0; j < 8; ++j){ fi[j] = (_Float16)pi[j]; fh[j] = (_Float16)ph[j]; }
      BI[q][kt] = fi; BH[q][kt] = fh;
    }
  }
  float bias[4];
  #pragma unroll
  for (int q = 0; q < 4; ++q){
    int col = q*kHH + wl*16 + lo;
    bias[q] = bi_[col] + bh_[col];
  }

  float c[kNU][4];
  #pragma unroll
  for (int u = 0; u < kNU; ++u){c[u][0]=0.f;c[u][1]=0.f;c[u][2]=0.f;c[u][3]=0.f;}
  half8 ax[kNU][2], axn[kNU][2];

  const _Float16* xrow[kNU];
  #pragma unroll
  for (int u = 0; u < kNU; ++u)
    xrow[u] = xin + (size_t)min(nb0 + u*16 + lo, kNN-1)*kTT*kHH;
  if (layer == 0){
    #pragma unroll
    for (int u = 0; u < kNU; ++u)
      #pragma unroll
      for (int kt = 0; kt < 2; ++kt)
        axn[u][kt] = *(const half8*)&xrow[u][kt*32 + hi4*8];
  }

  for (int i = 0; i < 13; ++i){
    int t = layer ? i-1 : i;
    bool act = layer ? (i >= 1) : (i < 12);
    if (act){
      if (layer == 0){
        // consume prefetched x, then immediately issue next-t loads — a full
        // step (~8000cy) of latency budget before use AND before the drain.
        #pragma unroll
        for (int u = 0; u < kNU; ++u){
          ax[u][0] = axn[u][0]; ax[u][1] = axn[u][1];
        }
        if (t < kTT-1){
          #pragma unroll
          for (int u = 0; u < kNU; ++u)
            #pragma unroll
            for (int kt = 0; kt < 2; ++kt)
              axn[u][kt] = *(const half8*)&xrow[u][(size_t)(t+1)*kHH + kt*32 + hi4*8];
        }
      }
      #pragma unroll
      for (int u = 0; u < kNU; ++u){
        // layer1 input = h0(t), written by layer0 in iter i-1 (buf t&1);
        // layer0 this iter writes buf (t+1)&1 -> no race.
        if (layer){
          const _Float16* rb = &h0b[u][t & 1][0];
          #pragma unroll
          for (int kt = 0; kt < 2; ++kt)
            ax[u][kt] = *(const half8*)&rb[lo*LP + kt*32 + hi4*8];
        }
        half8 ah[2];
        if (t > 0){
          // recurrent h(t-1): buf (t-1)&1, written iter i-1; this iter writes
          // buf t&1 -> no race.
          const _Float16* rb = layer ? &h1b[u][(t-1) & 1][0] : &h0b[u][(t-1) & 1][0];
          #pragma unroll
          for (int kt = 0; kt < 2; ++kt)
            ah[kt] = *(const half8*)&rb[lo*LP + kt*32 + hi4*8];
        }
        floatx4 acc[4];
        #pragma unroll
        for (int q = 0; q < 4; ++q){
          floatx4 a = {bias[q], bias[q], bias[q], bias[q]};
          a = __builtin_amdgcn_mfma_f32_16x16x32_f16(ax[u][0], BI[q][0], a, 0,0,0);
          a = __builtin_amdgcn_mfma_f32_16x16x32_f16(ax[u][1], BI[q][1], a, 0,0,0);
          acc[q] = a;
        }
        if (t > 0){
          #pragma unroll
          for (int q = 0; q < 4; ++q){
            floatx4 a = acc[q];
            a = __builtin_amdgcn_mfma_f32_16x16x32_f16(ah[0], BH[q][0], a, 0,0,0);
            a = __builtin_amdgcn_mfma_f32_16x16x32_f16(ah[1], BH[q][1], a, 0,0,0);
            acc[q] = a;
          }
        }
        _Float16* hb = layer ? &h1b[u][t & 1][0] : &h0b[u][t & 1][0];
        #pragma unroll
        for (int r = 0; r < 4; ++r){
          float ii = sigf(acc[0][r]);
          float ff = sigf(acc[1][r]);
          float gt = tanh_fast(acc[2][r]);
          float oo = sigf(acc[3][r]);
          c[u][r] = ff*c[u][r] + ii*gt;
          float hn = oo * tanh_fast(c[u][r]);
          hb[(hi4*4 + r)*LP + wl*16 + lo] = (_Float16)hn;
        }
      }
    }
    __syncthreads();
  }
  // FC: h1(t=11) sits in h1b[u][1]; waves 4..4+kNU-1 handle tiles 0..kNU-1.
  if (w >= 4 && w < 4 + kNU){
    int u = w - 4;
    const _Float16* rb = &h1b[u][1][0];
    half8 a0 = *(const half8*)&rb[lo*LP + 0*32 + hi4*8];
    half8 a1 = *(const half8*)&rb[lo*LP + 1*32 + hi4*8];
    half8 F0, F1;
    const float* pf = fcw + (size_t)lo*kHH + hi4*8;
    #pragma unroll
    for (int j = 0; j < 8; ++j){ F0[j] = (_Float16)pf[j]; F1[j] = (_Float16)pf[32+j]; }
    floatx4 a = {0.f,0.f,0.f,0.f};
    a = __builtin_amdgcn_mfma_f32_16x16x32_f16(a0, F0, a, 0,0,0);
    a = __builtin_amdgcn_mfma_f32_16x16x32_f16(a1, F1, a, 0,0,0);
    float bo = fcb[lo];
    #pragma unroll
    for (int r = 0; r < 4; ++r){
      int n = nb0 + u*16 + hi4*4 + r;
      if (n < kNN) out[(size_t)n*kOUT + lo] = a[r] + bo;
    }
  }
}

extern "C" void kernel_launch(void* const* d_in, const int* in_sizes, int n_in,
                              void* d_out, int out_size, void* d_ws, size_t ws_size,
                              hipStream_t stream){
  const float* x    = (const float*)d_in[0];
  const int*   ei   = (const int*)  d_in[1];
  const float* gw0  = (const float*)d_in[2];
  const float* gb0  = (const float*)d_in[3];
  const float* gw1  = (const float*)d_in[4];
  const float* gb1  = (const float*)d_in[5];
  const float* wih0 = (const float*)d_in[6];
  const float* whh0 = (const float*)d_in[7];
  const float* bih0 = (const float*)d_in[8];
  const float* bhh0 = (const float*)d_in[9];
  const float* wih1 = (const float*)d_in[10];
  const float* whh1 = (const float*)d_in[11];
  const float* bih1 = (const float*)d_in[12];
  const float* bhh1 = (const float*)d_in[13];
  const float* fcw  = (const float*)d_in[14];
  const float* fcb  = (const float*)d_in[15];
  float* out = (float*)d_out;

  char* ws = (char*)d_ws;
  size_t p = 0;
  auto carve = [&](size_t bytes)->char*{
    char* r = ws + p;
    p += (bytes + 255) & ~(size_t)255;
    return r;
  };
  int*   cnt  = (int*)  carve(sizeof(int)*kNN);
  int*   cur  = (int*)  carve(sizeof(int)*kNN);
  int*   pb   = (int*)  carve(sizeof(int)*kDB);
  int*   offs = (int*)  carve(sizeof(int)*(kNN+1));
  float* dis  = (float*)carve(sizeof(float)*kNN);
  int2*  edat = (int2*) carve(sizeof(int2)*kNE);
  _Float16* aggX = (_Float16*)carve(sizeof(_Float16)*(size_t)kNN*kTT*kFIN); // 7.68MB
  _Float16* bufA = (_Float16*)carve(sizeof(_Float16)*(size_t)kNN*kTT*kHH);  // 15.36MB
  _Float16* bufB = (_Float16*)carve(sizeof(_Float16)*(size_t)kNN*kTT*kHH);  // 15.36MB
  (void)ws_size; (void)in_sizes; (void)n_in; (void)out_size;

  // CSR prologue: detect(+cnt zero), deg, scan(+cur=offs), scatter.
  // No memset dispatch; no x-cast pass (k_agg gathers fp32 x directly).
  k_detect_zero<<<kDB, 256, 0, stream>>>(ei, pb, cnt);
  k_deg    <<<(kNE+255)/256, 256, 0, stream>>>(ei, pb, cnt);
  k_scan   <<<1, 1024, 0, stream>>>(cnt, offs, cur, dis);
  k_scatter<<<(kNE+255)/256, 256, 0, stream>>>(ei, pb, cur, dis, edat);

  // GCN-0: aggregate 32-feat fp32 x (A_hat x), then GEMM (+gb0+relu), t-major
  k_agg<kFIN, float><<<(kNN/2*(kTT/4) + 3)/4, 256, 0, stream>>>(x, aggX, dis, offs, edat);
  k_gemm<kFIN, kHH, false><<<(kNN*kTT)/64, 256, 0, stream>>>(aggX, gw0, gb0, bufB);
  // GCN-1: aggregate 64-feat, GEMM (+gb1+relu) writes node-major for LSTM
  k_agg<kHH, _Float16><<<(kNN/2*(kTT/2) + 3)/4, 256, 0, stream>>>(bufB, bufA, dis, offs, edat);
  k_gemm<kHH, kHH, true><<<(kNN*kTT)/64, 256, 0, stream>>>(bufA, gw1, gb1, bufB);

  // Fused 2-layer LSTM + FC -> out (three 16-node tiles per block)
  k_rec2<<<(kNN + 16*kNU - 1)/(16*kNU), 512, 0, stream>>>(bufB, wih0, whh0, bih0, bhh0,
                                          wih1, whh1, bih1, bhh1, fcw, fcb, out);
}